// Round 19
// baseline (84.302 us; speedup 1.0000x reference)
//
#include <hip/hip_runtime.h>
#include <math.h>

// B=256, P=40, S=60, D=64. Round-19 = Round-17 structure, but register
// budget controlled via PURE LLVM attributes (no __launch_bounds__):
//   amdgpu_flat_work_group_size(1024,1024)  -- exact WG size
//   amdgpu_waves_per_eu(1,4)                -- occupancy MAX 4 waves/EU
// R15/R16/R17/R18 all printed VGPR=64 (8 waves/EU allocator target) and
// ~80 MB scratch spill; __launch_bounds__ lowers to its own waves-per-eu
// minimum and overrode the (4,4) attribute in R18. With max=4 the allocator
// may use 512/4 = 128 VGPR; body's honest liveness ~120 (half-width GEMMs,
// x + weights in LDS).
//
// Register-chain trick: MFMA contraction is invariant to permuting the k-dim.
// C/D output holds the row-dim in-lane as {16mt+4g+j}; the next GEMM
// contracting that dim takes both operands by pure register reindexing:
//     frag[nt][ks] = pk16( acc2[2ks][nb], acc2[2ks+1][nb] )
// map pi(ks,i,g)=16*(2ks+(i>>2))+4g+(i&3). W1/W2 pre-permuted to pi-layout.
//
// Layout facts (cdna4 guide, measured m89/m91):
//   C/D: lane holds col=lane&15, rows 16mt+4(lane>>4)+j
//   A/B: row(col)=lane&15, kappa = 32ks+8(lane>>4)+i

typedef _Float16 half8 __attribute__((ext_vector_type(8)));
typedef __fp16 fp16x2 __attribute__((ext_vector_type(2)));
typedef float f4 __attribute__((ext_vector_type(4)));

#define MFMA16(a, b, c) __builtin_amdgcn_mfma_f32_16x16x32_f16((a), (b), (c), 0, 0, 0)

__global__ __launch_bounds__(256) void prep_weights(
    const float* __restrict__ Wq, const float* __restrict__ Wk,
    const float* __restrict__ Wv, const float* __restrict__ W1,
    const float* __restrict__ W2, _Float16* __restrict__ wsH) {
    int idx = blockIdx.x * 256 + threadIdx.x;  // 0..20479
    int m = idx >> 12, r = idx & 4095;
    const float* src = (m == 0) ? Wq : (m == 1) ? Wk : (m == 2) ? Wv
                        : (m == 3) ? W1 : W2;
    float v;
    if (m < 3) {
        v = src[r];  // natural row-major [e][d]
    } else {
        // pi-permuted: position (e, kappa) holds W[e][ d=16*(2ks+(i>>2))+4g+(i&3) ]
        int e = r >> 6, kp = r & 63;
        int ks = kp >> 5, gg = (kp >> 3) & 3, i = kp & 7;
        int d = 16 * (2 * ks + (i >> 2)) + 4 * gg + (i & 3);
        v = src[e * 64 + d];
    }
    wsH[idx] = (_Float16)v;
}

// Packed f32x4 + f32x4 -> half8 via v_cvt_pkrtz_f16_f32 (4 insts).
__device__ __forceinline__ half8 pk8(f4 a, f4 b) {
    union { half8 h; fp16x2 p[4]; } u;
    u.p[0] = __builtin_amdgcn_cvt_pkrtz(a[0], a[1]);
    u.p[1] = __builtin_amdgcn_cvt_pkrtz(a[2], a[3]);
    u.p[2] = __builtin_amdgcn_cvt_pkrtz(b[0], b[1]);
    u.p[3] = __builtin_amdgcn_cvt_pkrtz(b[2], b[3]);
    return u.h;
}

// Half-width GEMM: output cols restricted to nt in {2h, 2h+1}; acc2[4][2].
// AEXPR uses (t, ks); BEXPR uses (nt, ks); CEXPR uses (mt, nb, nt).
#define GEMM_H(AEXPR, BEXPR, CEXPR)                                          \
    do {                                                                     \
        _Pragma("unroll")                                                    \
        for (int ks = 0; ks < 2; ++ks) {                                     \
            half8 afr[4], bfr[2];                                            \
            _Pragma("unroll")                                                \
            for (int t = 0; t < 4; ++t) afr[t] = (AEXPR);                    \
            _Pragma("unroll")                                                \
            for (int nb = 0; nb < 2; ++nb) {                                 \
                const int nt = 2 * h + nb; (void)nt;                         \
                bfr[nb] = (BEXPR);                                           \
            }                                                                \
            _Pragma("unroll")                                                \
            for (int mt = 0; mt < 4; ++mt)                                   \
                _Pragma("unroll")                                            \
                for (int nb = 0; nb < 2; ++nb) {                             \
                    const int nt = 2 * h + nb; (void)nt;                     \
                    acc2[mt][nb] = MFMA16(afr[mt], bfr[nb],                  \
                                          ks == 0 ? (CEXPR) : acc2[mt][nb]); \
                }                                                            \
        }                                                                    \
    } while (0)

// acc2 -> pi-layout frags for this half (dst[2h+nb][ks]).
#define MKFR_H(dst, RELU)                                                    \
    do {                                                                     \
        _Pragma("unroll")                                                    \
        for (int nb = 0; nb < 2; ++nb)                                       \
            _Pragma("unroll")                                                \
            for (int ks = 0; ks < 2; ++ks) {                                 \
                f4 a_ = acc2[2 * ks][nb], b_ = acc2[2 * ks + 1][nb];         \
                if (RELU) {                                                  \
                    _Pragma("unroll")                                        \
                    for (int j = 0; j < 4; ++j) {                            \
                        a_[j] = fmaxf(a_[j], 0.f);                           \
                        b_[j] = fmaxf(b_[j], 0.f);                           \
                    }                                                        \
                }                                                            \
                dst[2 * h + nb][ks] = pk8(a_, b_);                           \
            }                                                                \
    } while (0)

// Weight fragment from LDS: matrix widx, row-block RB (row = 16*RB+lo),
// kappa chunk (32ks+8g), XOR-swizzled by (lo&7)<<3 halves.
#define WFRAG(widx, RB) (*(const half8*)&wlds[(widx) * 4096 + (16 * (RB) + lo) * 64 + \
                                              ((32 * ks + 8 * g) ^ ((lo & 7) << 3))])

// x fragment from LDS (rows >= 60 -> zero; constant-folds for RB < 3).
#define XFRAG(RB) __extension__({                                            \
    int row_ = 16 * (RB) + lo;                                               \
    int rowc_ = row_ < 60 ? row_ : 48;                                       \
    half8 v_ = *(const half8*)&wlds[xbase + rowc_ * 64 +                     \
                                    ((32 * ks + 8 * g) ^ ((lo & 7) << 3))];  \
    if (row_ >= 60) { half8 z_ = {}; v_ = z_; }                              \
    v_; })

__global__
__attribute__((amdgpu_flat_work_group_size(1024, 1024),
               amdgpu_waves_per_eu(1, 4))) void fused_f16(
    const float* __restrict__ x, const _Float16* __restrict__ wH,
    const float* __restrict__ bq, const float* __restrict__ bk,
    const float* __restrict__ bv, const float* __restrict__ b1,
    const float* __restrict__ b2, const float* __restrict__ W3,
    const float* __restrict__ b3, float* __restrict__ out) {
    // 40 KB weights + 16 x-tiles (60x64 f16, swizzled) = 163840 B = 160 KB.
    __shared__ __align__(16) _Float16 wlds[81920];

    const int tid = threadIdx.x;
    const int l = tid & 63;           // lane
    const int w = tid >> 6;           // wave 0..15 (one part each)
    const int lo = l & 15, g = l >> 4;

    // ---- cooperative weight load global->LDS with write-side swizzle.
    #pragma unroll
    for (int rep = 0; rep < 3; ++rep) {
        int chunk = rep * 1024 + tid;         // 0..2559 valid
        if (chunk < 2560) {
            int widx = chunk >> 9;
            int rem = chunk & 511;
            int row = rem >> 3, c = rem & 7;
            *(half8*)&wlds[widx * 4096 + row * 64 + ((c * 8) ^ ((row & 7) << 3))] =
                *(const half8*)&wH[widx * 4096 + row * 64 + c * 8];
        }
    }
    __syncthreads();  // weights visible to all; waves independent afterwards

    const int part = blockIdx.x * 16 + w;  // one part per wave
    const int xbase = 20480 + w * 3840;    // this wave's x tile (halves)
    const float* __restrict__ xp = x + (size_t)part * (60 * 64);

    // ---- stage this part's x into LDS (f16, swizzled). Own region, same-wave
    // in-order LDS -> no barrier needed.
    #pragma unroll
    for (int m = 0; m < 8; ++m) {
        int chunk = m * 64 + l;               // 480 16B-chunks (60 rows x 8)
        if (chunk < 480) {
            int row = chunk >> 3, c = chunk & 7;
            const float* p = xp + row * 64 + c * 8;
            half8 hv = pk8(*(const f4*)p, *(const f4*)(p + 4));
            *(half8*)&wlds[xbase + row * 64 + ((c * 8) ^ ((row & 7) << 3))] = hv;
        }
    }

    const f4 zc = {0.f, 0.f, 0.f, 0.f};
    f4 acc2[4][2];
    f4 brow[4];
    half8 qf[4][2], kf[4][2], vf[4][2], pf[4][2], wtf[4][2], h1f[4][2];

    // ---- qT = Wq * xT + bq
    #pragma unroll
    for (int mt = 0; mt < 4; ++mt) brow[mt] = *(const f4*)&bq[16 * mt + 4 * g];
    #pragma unroll
    for (int h = 0; h < 2; ++h) {
        GEMM_H(WFRAG(0, t), XFRAG(nt), brow[mt]);
        MKFR_H(qf, false);
    }

    // ---- kT = Wk * xT + bk
    #pragma unroll
    for (int mt = 0; mt < 4; ++mt) brow[mt] = *(const f4*)&bk[16 * mt + 4 * g];
    #pragma unroll
    for (int h = 0; h < 2; ++h) {
        GEMM_H(WFRAG(1, t), XFRAG(nt), brow[mt]);
        MKFR_H(kf, false);
    }

    // ---- scoresT + softmax + P, per half (A = kf regs, B = qf half)
    #pragma unroll
    for (int h = 0; h < 2; ++h) {
        GEMM_H(kf[t][ks], qf[nt][ks], zc);
        #pragma unroll
        for (int nb = 0; nb < 2; ++nb) {
            float sum = 0.f;
            #pragma unroll
            for (int mt = 0; mt < 4; ++mt)
                #pragma unroll
                for (int j = 0; j < 4; ++j) {
                    float e = (mt == 3 && g == 3)
                                  ? 0.f
                                  : exp2f(acc2[mt][nb][j] * 0.1803368801111137f);
                    acc2[mt][nb][j] = e;
                    sum += e;
                }
            sum += __shfl_xor(sum, 16);
            sum += __shfl_xor(sum, 32);
            float inv = 1.f / sum;
            #pragma unroll
            for (int mt = 0; mt < 4; ++mt)
                #pragma unroll
                for (int j = 0; j < 4; ++j) acc2[mt][nb][j] *= inv;
        }
        MKFR_H(pf, false);
    }
    // qf, kf dead here.

    // ---- v = x * WvT + bv (col-splat C-in), per half
    #pragma unroll
    for (int h = 0; h < 2; ++h) {
        float bc[2];
        #pragma unroll
        for (int nb = 0; nb < 2; ++nb) bc[nb] = bv[16 * (2 * h + nb) + lo];
        GEMM_H(XFRAG(t), WFRAG(2, nt),
               ((f4){bc[nb], bc[nb], bc[nb], bc[nb]}));
        MKFR_H(vf, false);
    }

    // ---- weightedT = vT * P, per half (A = vf regs, B = pf half)
    #pragma unroll
    for (int h = 0; h < 2; ++h) {
        GEMM_H(vf[t][ks], pf[nt][ks], zc);
        MKFR_H(wtf, false);
    }
    // vf, pf dead here.

    // ---- h1T = relu(W1 * weightedT + b1)   (W1 pi-permuted)
    #pragma unroll
    for (int mt = 0; mt < 4; ++mt) brow[mt] = *(const f4*)&b1[16 * mt + 4 * g];
    #pragma unroll
    for (int h = 0; h < 2; ++h) {
        GEMM_H(WFRAG(3, t), wtf[nt][ks], brow[mt]);
        MKFR_H(h1f, true);
    }

    // ---- h2T = relu(W2 * h1T + b2), head folded per half on f32 acc
    #pragma unroll
    for (int mt = 0; mt < 4; ++mt) brow[mt] = *(const f4*)&b2[16 * mt + 4 * g];
    f4 w3r[4];
    #pragma unroll
    for (int mt = 0; mt < 4; ++mt) w3r[mt] = *(const f4*)&W3[16 * mt + 4 * g];
    float b3v = b3[0];
    #pragma unroll
    for (int h = 0; h < 2; ++h) {
        GEMM_H(WFRAG(4, t), h1f[nt][ks], brow[mt]);
        #pragma unroll
        for (int nb = 0; nb < 2; ++nb) {
            float sres = 0.f;
            #pragma unroll
            for (int mt = 0; mt < 4; ++mt)
                #pragma unroll
                for (int j = 0; j < 4; ++j)
                    sres += fmaxf(acc2[mt][nb][j], 0.f) * w3r[mt][j];
            sres += __shfl_xor(sres, 16);
            sres += __shfl_xor(sres, 32);
            if (g == 0) {
                int s = 16 * (2 * h + nb) + lo;
                if (s < 60) out[(size_t)part * 60 + s] = sres + b3v;
            }
        }
    }
}

extern "C" void kernel_launch(void* const* d_in, const int* in_sizes, int n_in,
                              void* d_out, int out_size, void* d_ws, size_t ws_size,
                              hipStream_t stream) {
    const float* x  = (const float*)d_in[0];
    const float* Wq = (const float*)d_in[1];
    const float* bq = (const float*)d_in[2];
    const float* Wk = (const float*)d_in[3];
    const float* bk = (const float*)d_in[4];
    const float* Wv = (const float*)d_in[5];
    const float* bv = (const float*)d_in[6];
    const float* W1 = (const float*)d_in[7];
    const float* b1 = (const float*)d_in[8];
    const float* W2 = (const float*)d_in[9];
    const float* b2 = (const float*)d_in[10];
    const float* W3 = (const float*)d_in[11];
    const float* b3 = (const float*)d_in[12];
    _Float16* wsH = (_Float16*)d_ws;  // 5 * 4096 halves = 40 KB

    prep_weights<<<80, 256, 0, stream>>>(Wq, Wk, Wv, W1, W2, wsH);
    // 640 WGs x 1024 thr = 16 waves/WG = 4 waves/SIMD; one part per wave;
    // weights + per-wave x tiles in LDS (160 KB); waves_per_eu max 4 -> 128 VGPR.
    fused_f16<<<640, 1024, 0, stream>>>(x, wsH, bq, bk, bv, b1, b2, W3, b3,
                                        (float*)d_out);
}

// Round 20
// 69.917 us; speedup vs baseline: 1.2057x; 1.2057x over previous
//
#include <hip/hip_runtime.h>
#include <math.h>

// B=256, P=40, S=60, D=64. Round-20 = Round-17 structure in a 512-thread WG.
// R17/R18/R19 proved hipcc pins flat-work-group-size=1024 kernels at 64 VGPR
// unconditionally (launch_bounds arg2, waves_per_eu(4,4), pure attributes all
// ignored) -> ~12 KB/part scratch round-trip = the 84 us wall. (256,1) and
// (256-thr,1) kernels were NEVER pinned (allocator used 124-256 as needed).
// So: 512-thr WG (8 waves = 2/SIMD min -> HW cap 256), launch_bounds(512,1);
// the ~120-reg honest body (x+weights in LDS, half-width GEMMs) fits with
// NO spill. LDS = 40 KB weights + 8 x 7.5 KB x-tiles = 100 KB -> 1 WG/CU,
// 8 waves/CU residency; 1280 WGs x 8 parts.
//
// Register-chain trick: MFMA contraction is invariant to permuting the k-dim.
// C/D output holds the row-dim in-lane as {16mt+4g+j}; the next GEMM
// contracting that dim takes both operands by pure register reindexing:
//     frag[nt][ks] = pk16( acc2[2ks][nb], acc2[2ks+1][nb] )
// map pi(ks,i,g)=16*(2ks+(i>>2))+4g+(i&3). W1/W2 pre-permuted to pi-layout.
//
// Layout facts (cdna4 guide, measured m89/m91):
//   C/D: lane holds col=lane&15, rows 16mt+4(lane>>4)+j
//   A/B: row(col)=lane&15, kappa = 32ks+8(lane>>4)+i

typedef _Float16 half8 __attribute__((ext_vector_type(8)));
typedef __fp16 fp16x2 __attribute__((ext_vector_type(2)));
typedef float f4 __attribute__((ext_vector_type(4)));

#define MFMA16(a, b, c) __builtin_amdgcn_mfma_f32_16x16x32_f16((a), (b), (c), 0, 0, 0)

__global__ __launch_bounds__(256) void prep_weights(
    const float* __restrict__ Wq, const float* __restrict__ Wk,
    const float* __restrict__ Wv, const float* __restrict__ W1,
    const float* __restrict__ W2, _Float16* __restrict__ wsH) {
    int idx = blockIdx.x * 256 + threadIdx.x;  // 0..20479
    int m = idx >> 12, r = idx & 4095;
    const float* src = (m == 0) ? Wq : (m == 1) ? Wk : (m == 2) ? Wv
                        : (m == 3) ? W1 : W2;
    float v;
    if (m < 3) {
        v = src[r];  // natural row-major [e][d]
    } else {
        // pi-permuted: position (e, kappa) holds W[e][ d=16*(2ks+(i>>2))+4g+(i&3) ]
        int e = r >> 6, kp = r & 63;
        int ks = kp >> 5, gg = (kp >> 3) & 3, i = kp & 7;
        int d = 16 * (2 * ks + (i >> 2)) + 4 * gg + (i & 3);
        v = src[e * 64 + d];
    }
    wsH[idx] = (_Float16)v;
}

// Packed f32x4 + f32x4 -> half8 via v_cvt_pkrtz_f16_f32 (4 insts).
__device__ __forceinline__ half8 pk8(f4 a, f4 b) {
    union { half8 h; fp16x2 p[4]; } u;
    u.p[0] = __builtin_amdgcn_cvt_pkrtz(a[0], a[1]);
    u.p[1] = __builtin_amdgcn_cvt_pkrtz(a[2], a[3]);
    u.p[2] = __builtin_amdgcn_cvt_pkrtz(b[0], b[1]);
    u.p[3] = __builtin_amdgcn_cvt_pkrtz(b[2], b[3]);
    return u.h;
}

// Half-width GEMM: output cols restricted to nt in {2h, 2h+1}; acc2[4][2].
// AEXPR uses (t, ks); BEXPR uses (nt, ks); CEXPR uses (mt, nb, nt).
#define GEMM_H(AEXPR, BEXPR, CEXPR)                                          \
    do {                                                                     \
        _Pragma("unroll")                                                    \
        for (int ks = 0; ks < 2; ++ks) {                                     \
            half8 afr[4], bfr[2];                                            \
            _Pragma("unroll")                                                \
            for (int t = 0; t < 4; ++t) afr[t] = (AEXPR);                    \
            _Pragma("unroll")                                                \
            for (int nb = 0; nb < 2; ++nb) {                                 \
                const int nt = 2 * h + nb; (void)nt;                         \
                bfr[nb] = (BEXPR);                                           \
            }                                                                \
            _Pragma("unroll")                                                \
            for (int mt = 0; mt < 4; ++mt)                                   \
                _Pragma("unroll")                                            \
                for (int nb = 0; nb < 2; ++nb) {                             \
                    const int nt = 2 * h + nb; (void)nt;                     \
                    acc2[mt][nb] = MFMA16(afr[mt], bfr[nb],                  \
                                          ks == 0 ? (CEXPR) : acc2[mt][nb]); \
                }                                                            \
        }                                                                    \
    } while (0)

// acc2 -> pi-layout frags for this half (dst[2h+nb][ks]).
#define MKFR_H(dst, RELU)                                                    \
    do {                                                                     \
        _Pragma("unroll")                                                    \
        for (int nb = 0; nb < 2; ++nb)                                       \
            _Pragma("unroll")                                                \
            for (int ks = 0; ks < 2; ++ks) {                                 \
                f4 a_ = acc2[2 * ks][nb], b_ = acc2[2 * ks + 1][nb];         \
                if (RELU) {                                                  \
                    _Pragma("unroll")                                        \
                    for (int j = 0; j < 4; ++j) {                            \
                        a_[j] = fmaxf(a_[j], 0.f);                           \
                        b_[j] = fmaxf(b_[j], 0.f);                           \
                    }                                                        \
                }                                                            \
                dst[2 * h + nb][ks] = pk8(a_, b_);                           \
            }                                                                \
    } while (0)

// Weight fragment from LDS: matrix widx, row-block RB (row = 16*RB+lo),
// kappa chunk (32ks+8g), XOR-swizzled by (lo&7)<<3 halves.
#define WFRAG(widx, RB) (*(const half8*)&wlds[(widx) * 4096 + (16 * (RB) + lo) * 64 + \
                                              ((32 * ks + 8 * g) ^ ((lo & 7) << 3))])

// x fragment from LDS (rows >= 60 -> zero; constant-folds for RB < 3).
#define XFRAG(RB) __extension__({                                            \
    int row_ = 16 * (RB) + lo;                                               \
    int rowc_ = row_ < 60 ? row_ : 48;                                       \
    half8 v_ = *(const half8*)&wlds[xbase + rowc_ * 64 +                     \
                                    ((32 * ks + 8 * g) ^ ((lo & 7) << 3))];  \
    if (row_ >= 60) { half8 z_ = {}; v_ = z_; }                              \
    v_; })

__global__ __launch_bounds__(512, 1) void fused_f16(
    const float* __restrict__ x, const _Float16* __restrict__ wH,
    const float* __restrict__ bq, const float* __restrict__ bk,
    const float* __restrict__ bv, const float* __restrict__ b1,
    const float* __restrict__ b2, const float* __restrict__ W3,
    const float* __restrict__ b3, float* __restrict__ out) {
    // 40 KB weights + 8 x-tiles (60x64 f16, swizzled) = 102400 B = 100 KB.
    __shared__ __align__(16) _Float16 wlds[51200];

    const int tid = threadIdx.x;
    const int l = tid & 63;           // lane
    const int w = tid >> 6;           // wave 0..7 (one part each)
    const int lo = l & 15, g = l >> 4;

    // ---- cooperative weight load global->LDS with write-side swizzle.
    #pragma unroll
    for (int rep = 0; rep < 5; ++rep) {
        int chunk = rep * 512 + tid;          // 0..2559
        int widx = chunk >> 9;
        int rem = chunk & 511;
        int row = rem >> 3, c = rem & 7;
        *(half8*)&wlds[widx * 4096 + row * 64 + ((c * 8) ^ ((row & 7) << 3))] =
            *(const half8*)&wH[widx * 4096 + row * 64 + c * 8];
    }
    __syncthreads();  // weights visible to all; waves independent afterwards

    const int part = blockIdx.x * 8 + w;   // one part per wave
    const int xbase = 20480 + w * 3840;    // this wave's x tile (halves)
    const float* __restrict__ xp = x + (size_t)part * (60 * 64);

    // ---- stage this part's x into LDS (f16, swizzled). Own region, same-wave
    // in-order LDS -> no barrier needed.
    #pragma unroll
    for (int m = 0; m < 8; ++m) {
        int chunk = m * 64 + l;               // 480 16B-chunks (60 rows x 8)
        if (chunk < 480) {
            int row = chunk >> 3, c = chunk & 7;
            const float* p = xp + row * 64 + c * 8;
            half8 hv = pk8(*(const f4*)p, *(const f4*)(p + 4));
            *(half8*)&wlds[xbase + row * 64 + ((c * 8) ^ ((row & 7) << 3))] = hv;
        }
    }

    const f4 zc = {0.f, 0.f, 0.f, 0.f};
    f4 acc2[4][2];
    f4 brow[4];
    half8 qf[4][2], kf[4][2], vf[4][2], pf[4][2], wtf[4][2], h1f[4][2];

    // ---- qT = Wq * xT + bq
    #pragma unroll
    for (int mt = 0; mt < 4; ++mt) brow[mt] = *(const f4*)&bq[16 * mt + 4 * g];
    #pragma unroll
    for (int h = 0; h < 2; ++h) {
        GEMM_H(WFRAG(0, t), XFRAG(nt), brow[mt]);
        MKFR_H(qf, false);
    }

    // ---- kT = Wk * xT + bk
    #pragma unroll
    for (int mt = 0; mt < 4; ++mt) brow[mt] = *(const f4*)&bk[16 * mt + 4 * g];
    #pragma unroll
    for (int h = 0; h < 2; ++h) {
        GEMM_H(WFRAG(1, t), XFRAG(nt), brow[mt]);
        MKFR_H(kf, false);
    }

    // ---- scoresT + softmax + P, per half (A = kf regs, B = qf half)
    #pragma unroll
    for (int h = 0; h < 2; ++h) {
        GEMM_H(kf[t][ks], qf[nt][ks], zc);
        #pragma unroll
        for (int nb = 0; nb < 2; ++nb) {
            float sum = 0.f;
            #pragma unroll
            for (int mt = 0; mt < 4; ++mt)
                #pragma unroll
                for (int j = 0; j < 4; ++j) {
                    float e = (mt == 3 && g == 3)
                                  ? 0.f
                                  : exp2f(acc2[mt][nb][j] * 0.1803368801111137f);
                    acc2[mt][nb][j] = e;
                    sum += e;
                }
            sum += __shfl_xor(sum, 16);
            sum += __shfl_xor(sum, 32);
            float inv = 1.f / sum;
            #pragma unroll
            for (int mt = 0; mt < 4; ++mt)
                #pragma unroll
                for (int j = 0; j < 4; ++j) acc2[mt][nb][j] *= inv;
        }
        MKFR_H(pf, false);
    }
    // qf, kf dead here.

    // ---- v = x * WvT + bv (col-splat C-in), per half
    #pragma unroll
    for (int h = 0; h < 2; ++h) {
        float bc[2];
        #pragma unroll
        for (int nb = 0; nb < 2; ++nb) bc[nb] = bv[16 * (2 * h + nb) + lo];
        GEMM_H(XFRAG(t), WFRAG(2, nt),
               ((f4){bc[nb], bc[nb], bc[nb], bc[nb]}));
        MKFR_H(vf, false);
    }

    // ---- weightedT = vT * P, per half (A = vf regs, B = pf half)
    #pragma unroll
    for (int h = 0; h < 2; ++h) {
        GEMM_H(vf[t][ks], pf[nt][ks], zc);
        MKFR_H(wtf, false);
    }
    // vf, pf dead here.

    // ---- h1T = relu(W1 * weightedT + b1)   (W1 pi-permuted)
    #pragma unroll
    for (int mt = 0; mt < 4; ++mt) brow[mt] = *(const f4*)&b1[16 * mt + 4 * g];
    #pragma unroll
    for (int h = 0; h < 2; ++h) {
        GEMM_H(WFRAG(3, t), wtf[nt][ks], brow[mt]);
        MKFR_H(h1f, true);
    }

    // ---- h2T = relu(W2 * h1T + b2), head folded per half on f32 acc
    #pragma unroll
    for (int mt = 0; mt < 4; ++mt) brow[mt] = *(const f4*)&b2[16 * mt + 4 * g];
    f4 w3r[4];
    #pragma unroll
    for (int mt = 0; mt < 4; ++mt) w3r[mt] = *(const f4*)&W3[16 * mt + 4 * g];
    float b3v = b3[0];
    #pragma unroll
    for (int h = 0; h < 2; ++h) {
        GEMM_H(WFRAG(4, t), h1f[nt][ks], brow[mt]);
        #pragma unroll
        for (int nb = 0; nb < 2; ++nb) {
            float sres = 0.f;
            #pragma unroll
            for (int mt = 0; mt < 4; ++mt)
                #pragma unroll
                for (int j = 0; j < 4; ++j)
                    sres += fmaxf(acc2[mt][nb][j], 0.f) * w3r[mt][j];
            sres += __shfl_xor(sres, 16);
            sres += __shfl_xor(sres, 32);
            if (g == 0) {
                int s = 16 * (2 * h + nb) + lo;
                if (s < 60) out[(size_t)part * 60 + s] = sres + b3v;
            }
        }
    }
}

extern "C" void kernel_launch(void* const* d_in, const int* in_sizes, int n_in,
                              void* d_out, int out_size, void* d_ws, size_t ws_size,
                              hipStream_t stream) {
    const float* x  = (const float*)d_in[0];
    const float* Wq = (const float*)d_in[1];
    const float* bq = (const float*)d_in[2];
    const float* Wk = (const float*)d_in[3];
    const float* bk = (const float*)d_in[4];
    const float* Wv = (const float*)d_in[5];
    const float* bv = (const float*)d_in[6];
    const float* W1 = (const float*)d_in[7];
    const float* b1 = (const float*)d_in[8];
    const float* W2 = (const float*)d_in[9];
    const float* b2 = (const float*)d_in[10];
    const float* W3 = (const float*)d_in[11];
    const float* b3 = (const float*)d_in[12];
    _Float16* wsH = (_Float16*)d_ws;  // 5 * 4096 halves = 40 KB

    prep_weights<<<80, 256, 0, stream>>>(Wq, Wk, Wv, W1, W2, wsH);
    // 1280 WGs x 512 thr = 8 waves/WG, one part per wave; weights + per-wave
    // x tiles in LDS (100 KB); launch_bounds(512,1) -> honest VGPR (~120-160).
    fused_f16<<<1280, 512, 0, stream>>>(x, wsH, bq, bk, bv, b1, b2, W3, b3,
                                        (float*)d_out);
}